// Round 7
// baseline (689.861 us; speedup 1.0000x reference)
//
#include <hip/hip_runtime.h>
#include <hip/hip_bf16.h>

typedef __bf16 bf16x8 __attribute__((ext_vector_type(8)));
typedef float f32x4 __attribute__((ext_vector_type(4)));
using bf16 = __hip_bfloat16;

constexpr int T = 2048;
constexpr int M = 8 * 2048;   // B*T rows

__device__ inline float ldf(const void* p, size_t i, int isf32) {
  if (isf32) return ((const float*)p)[i];
  unsigned u = ((const unsigned short*)p)[i];
  return __uint_as_float(u << 16);
}
__device__ inline float bf2f(unsigned short u) { return __uint_as_float((unsigned)u << 16); }
__device__ inline unsigned short bfb(float x) {
  __hip_bfloat16 h = __float2bfloat16(x);
  return *reinterpret_cast<unsigned short*>(&h);
}

// ---------------- dtype probe + param conversion ----------------
struct PPtrs { const void* p[12]; };

__global__ void detect_convert_k(const void* __restrict__ item, PPtrs ps,
                                 float* __restrict__ params, int* __restrict__ flagp) {
  __shared__ int cnt[4];
  __shared__ int flagLDS;
  int tid = threadIdx.x;
  unsigned short lo = ((const unsigned short*)item)[tid * 2];
  float a = fabsf(bf2f(lo));
  bool okb = (a > 1e-5f) && (a < 0.5f);
  unsigned long long m = __ballot(okb);
  if ((tid & 63) == 0) cnt[tid >> 6] = __popcll(m);
  __syncthreads();
  if (tid == 0) {
    int tot = cnt[0] + cnt[1] + cnt[2] + cnt[3];
    int f = (tot < 128) ? 1 : 0;  // 1 = inputs are float32
    flagLDS = f; *flagp = f;
  }
  __syncthreads();
  int f = flagLDS;
  const int lens[12] = {128, 512, 512, 512, 128, 512, 512, 512, 512, 512, 512, 512};
  int off = 0;
  for (int j = 0; j < 12; ++j) {
    for (int i = tid; i < lens[j]; i += 256) params[off + i] = ldf(ps.p[j], i, f);
    off += lens[j];
  }
}

// ---------------- weight transpose: W[K][N] -> WT[N][K] ----------------
struct WPtrs { const void* p[7]; };

__global__ void transpose_w_k(WPtrs w, bf16* __restrict__ dst, const int* __restrict__ flagp) {
  int f = *flagp;
  int l = blockIdx.x, wi = blockIdx.y;
  const void* s = w.p[wi];
  size_t sbase = (size_t)l * 16384;
  bf16* d = dst + ((size_t)wi * 4 + l) * 16384;
  for (int i = 0; i < 64; ++i) {
    int e = i * 256 + threadIdx.x;                       // e = n*128 + k
    d[e] = __float2bfloat16(ldf(s, sbase + (size_t)(e & 127) * 128 + (e >> 7), f));
  }
}

// ---------------- shared GEMM-stage helpers (all wave-private, no barriers) ----------------
// W fragments straight from global (L2-hot): w[kk][nt] = WT[nt*16+l16][kk*32+quad*8 ..+7]
__device__ inline void issueW(const bf16* wt, bf16x8 (&w)[4][8], int quad, int l16) {
  #pragma unroll
  for (int kk = 0; kk < 4; ++kk)
    #pragma unroll
    for (int nt = 0; nt < 8; ++nt)
      w[kk][nt] = *(const bf16x8*)(wt + (size_t)(nt * 16 + l16) * 128 + kk * 32 + quad * 8);
}
__device__ inline void mfma_stage(const bf16x8 (&a)[4], const bf16x8 (&w)[4][8], f32x4 (&acc)[8]) {
  #pragma unroll
  for (int kk = 0; kk < 4; ++kk)
    #pragma unroll
    for (int nt = 0; nt < 8; ++nt)
      acc[nt] = __builtin_amdgcn_mfma_f32_16x16x32_bf16(a[kk], w[kk][nt], acc[nt], 0, 0, 0);
}
__device__ inline void zero8(f32x4 (&acc)[8]) {
  #pragma unroll
  for (int i = 0; i < 8; ++i) acc[i] = (f32x4){0.f, 0.f, 0.f, 0.f};
}
__device__ inline void readA(const bf16* aw, bf16x8 (&a)[4], int quad, int l16) {
  #pragma unroll
  for (int kk = 0; kk < 4; ++kk)
    a[kk] = *(const bf16x8*)&aw[l16 * 136 + kk * 32 + quad * 8];
}
// xr[nt][r] C-layout: row quad*4+r, col nt*16+l16. Builds A = rms(row)*scale into aw.
__device__ inline void buildA_rms(const float (&xr)[8][4], const float* scale, bf16* aw,
                                  int quad, int l16) {
  float s8[8];
  #pragma unroll
  for (int nt = 0; nt < 8; ++nt) s8[nt] = scale[nt * 16 + l16];
  #pragma unroll
  for (int r = 0; r < 4; ++r) {
    float ss = 0.f;
    #pragma unroll
    for (int nt = 0; nt < 8; ++nt) ss += xr[nt][r] * xr[nt][r];
    ss += __shfl_xor(ss, 1); ss += __shfl_xor(ss, 2);
    ss += __shfl_xor(ss, 4); ss += __shfl_xor(ss, 8);
    float rs = rsqrtf(ss * (1.f / 128.f) + 1e-8f);
    #pragma unroll
    for (int nt = 0; nt < 8; ++nt)
      aw[(quad * 4 + r) * 136 + nt * 16 + l16] = __float2bfloat16(xr[nt][r] * rs * s8[nt]);
  }
}
__device__ inline void epi_silu_store(const f32x4 (&acc)[8], const float* bias, bf16* outg,
                                      int row0, int quad, int l16, float mulf) {
  #pragma unroll
  for (int nt = 0; nt < 8; ++nt) {
    int col = nt * 16 + l16; float bv = bias[col];
    #pragma unroll
    for (int r = 0; r < 4; ++r) {
      float v = acc[nt][r] + bv;
      v = v / (1.f + __expf(-v)) * mulf;
      outg[(size_t)(row0 + quad * 4 + r) * 128 + col] = __float2bfloat16(v);
    }
  }
}
__device__ inline void epi_silu_vt(const f32x4 (&acc)[8], const float* bias, bf16* vtg,
                                   int row0, int quad, int l16) {
  #pragma unroll
  for (int nt = 0; nt < 8; ++nt) {
    int col = nt * 16 + l16; float bv = bias[col];
    int h = col >> 6, hd = col & 63;
    #pragma unroll
    for (int r = 0; r < 4; ++r) {
      int gr = row0 + quad * 4 + r; int b = gr >> 11, t = gr & 2047;
      float v = acc[nt][r] + bv; v = v / (1.f + __expf(-v));
      vtg[((size_t)(b * 2 + h) * 64 + hd) * 2048 + t] = __float2bfloat16(v);
    }
  }
}
__device__ inline void epi_addx(const f32x4 (&acc)[8], const float* bias, float (&xr)[8][4],
                                int l16) {
  #pragma unroll
  for (int nt = 0; nt < 8; ++nt) {
    float bv = bias[nt * 16 + l16];
    #pragma unroll
    for (int r = 0; r < 4; ++r) xr[nt][r] += acc[nt][r] + bv;
  }
}

// QKVU stages for layer lnext: A = rms(xr)*ln1 shared across the 4 weight matrices.
// Q is pre-scaled by 0.125 (exact in bf16) so flash skips the per-element logits scale.
__device__ inline void qkvu_stages(const float (&xr)[8][4], bf16* aw, const bf16* wT,
    const float* params, int lnext, bf16* Ug, bf16* Qg, bf16* Kg, bf16* VTg,
    int row0, int quad, int l16) {
  buildA_rms(xr, params + 128 + lnext * 128, aw, quad, l16);
  bf16x8 a[4]; readA(aw, a, quad, l16);
  bf16x8 w[4][8]; f32x4 acc[8];
  const float* pb = params + 1792;
  issueW(wT + (size_t)(0 * 4 + lnext) * 16384, w, quad, l16);      // U
  zero8(acc); mfma_stage(a, w, acc);
  issueW(wT + (size_t)(1 * 4 + lnext) * 16384, w, quad, l16);      // V
  epi_silu_store(acc, pb + 0 * 512 + lnext * 128, Ug, row0, quad, l16, 1.f);
  zero8(acc); mfma_stage(a, w, acc);
  issueW(wT + (size_t)(2 * 4 + lnext) * 16384, w, quad, l16);      // Q
  epi_silu_vt(acc, pb + 1 * 512 + lnext * 128, VTg, row0, quad, l16);
  zero8(acc); mfma_stage(a, w, acc);
  issueW(wT + (size_t)(3 * 4 + lnext) * 16384, w, quad, l16);      // K
  epi_silu_store(acc, pb + 2 * 512 + lnext * 128, Qg, row0, quad, l16, 0.125f);
  zero8(acc); mfma_stage(a, w, acc);
  epi_silu_store(acc, pb + 3 * 512 + lnext * 128, Kg, row0, quad, l16, 1.f);
}

// ---------------- pre: embed + rms + QKVU(0). Barrier-free, wave owns 16 rows ----------------
__global__ __launch_bounds__(256) void pre_k(const int* __restrict__ seqs,
    const void* __restrict__ item, const void* __restrict__ pos, const bf16* __restrict__ wT,
    const float* __restrict__ params, float* __restrict__ xg, bf16* __restrict__ Ug,
    bf16* __restrict__ Qg, bf16* __restrict__ Kg, bf16* __restrict__ VTg,
    const int* __restrict__ flagp) {
  __shared__ __align__(16) bf16 awAll[4][16 * 136 + 8];
  int f = *flagp;
  int tid = threadIdx.x, wv = tid >> 6, lane = tid & 63, quad = lane >> 4, l16 = lane & 15;
  bf16* aw = awAll[wv];
  int row0 = blockIdx.x * 64 + wv * 16;
  int idxs[4];
  #pragma unroll
  for (int r = 0; r < 4; ++r) idxs[r] = seqs[row0 + quad * 4 + r];
  float xr[8][4];
  #pragma unroll
  for (int nt = 0; nt < 8; ++nt) {
    int col = nt * 16 + l16;
    #pragma unroll
    for (int r = 0; r < 4; ++r) {
      int gr = row0 + quad * 4 + r; int t = gr & 2047;
      xr[nt][r] = ldf(item, (size_t)idxs[r] * 128 + col, f)
                + ldf(pos, (size_t)(t + 1) * 128 + col, f);
    }
  }
  {  // x = rms(e)*emb_s
    float s8[8];
    #pragma unroll
    for (int nt = 0; nt < 8; ++nt) s8[nt] = params[nt * 16 + l16];
    #pragma unroll
    for (int r = 0; r < 4; ++r) {
      float ss = 0.f;
      #pragma unroll
      for (int nt = 0; nt < 8; ++nt) ss += xr[nt][r] * xr[nt][r];
      ss += __shfl_xor(ss, 1); ss += __shfl_xor(ss, 2);
      ss += __shfl_xor(ss, 4); ss += __shfl_xor(ss, 8);
      float rs = rsqrtf(ss * (1.f / 128.f) + 1e-8f);
      #pragma unroll
      for (int nt = 0; nt < 8; ++nt) xr[nt][r] *= rs * s8[nt];
    }
  }
  #pragma unroll
  for (int nt = 0; nt < 8; ++nt)
    #pragma unroll
    for (int r = 0; r < 4; ++r)
      xg[(size_t)(row0 + quad * 4 + r) * 128 + nt * 16 + l16] = xr[nt][r];
  qkvu_stages(xr, aw, wT, params, 0, Ug, Qg, Kg, VTg, row0, quad, l16);
}

// ---------------- post: f2+FFN for layer l, then QKVU(l+1) or final out ----------------
__global__ __launch_bounds__(256) void post_k(int l, float* __restrict__ xg,
    const float* __restrict__ avg, bf16* __restrict__ Ug, bf16* __restrict__ Qg,
    bf16* __restrict__ Kg, bf16* __restrict__ VTg, const bf16* __restrict__ wT,
    const float* __restrict__ params, void* __restrict__ dout, const int* __restrict__ flagp) {
  __shared__ __align__(16) bf16 awAll[4][16 * 136 + 8];
  int tid = threadIdx.x, wv = tid >> 6, lane = tid & 63, quad = lane >> 4, l16 = lane & 15;
  bf16* aw = awAll[wv];
  int row0 = blockIdx.x * 64 + wv * 16;
  bf16x8 w[4][8]; f32x4 acc[8];
  issueW(wT + (size_t)(16 + l) * 16384, w, quad, l16);             // f2
  float xr[8][4], av[8][4], uu[8][4];
  #pragma unroll
  for (int nt = 0; nt < 8; ++nt) {
    int col = nt * 16 + l16;
    #pragma unroll
    for (int r = 0; r < 4; ++r) {
      size_t off = (size_t)(row0 + quad * 4 + r) * 128 + col;
      xr[nt][r] = xg[off];
      av[nt][r] = avg[off];
      uu[nt][r] = bf2f(((const unsigned short*)Ug)[off]);
    }
  }
  {  // A = rms(av)*hstu_s*U
    const float* hs = params + 640 + l * 128;
    float s8[8];
    #pragma unroll
    for (int nt = 0; nt < 8; ++nt) s8[nt] = hs[nt * 16 + l16];
    #pragma unroll
    for (int r = 0; r < 4; ++r) {
      float ss = 0.f;
      #pragma unroll
      for (int nt = 0; nt < 8; ++nt) ss += av[nt][r] * av[nt][r];
      ss += __shfl_xor(ss, 1); ss += __shfl_xor(ss, 2);
      ss += __shfl_xor(ss, 4); ss += __shfl_xor(ss, 8);
      float rs = rsqrtf(ss * (1.f / 128.f) + 1e-8f);
      #pragma unroll
      for (int nt = 0; nt < 8; ++nt)
        aw[(quad * 4 + r) * 136 + nt * 16 + l16] =
            __float2bfloat16(av[nt][r] * rs * s8[nt] * uu[nt][r]);
    }
  }
  bf16x8 a[4]; readA(aw, a, quad, l16);
  zero8(acc); mfma_stage(a, w, acc);
  issueW(wT + (size_t)(20 + l) * 16384, w, quad, l16);             // c1
  epi_addx(acc, params + 3840 + l * 128, xr, l16);                 // x += f2
  buildA_rms(xr, params + 1152 + l * 128, aw, quad, l16);          // ln2
  readA(aw, a, quad, l16);
  zero8(acc); mfma_stage(a, w, acc);
  issueW(wT + (size_t)(24 + l) * 16384, w, quad, l16);             // c2
  {  // gelu -> aw (A of c2)
    const float* bb = params + 4352 + l * 128;
    #pragma unroll
    for (int nt = 0; nt < 8; ++nt) {
      int col = nt * 16 + l16; float bv = bb[col];
      #pragma unroll
      for (int r = 0; r < 4; ++r) {
        float v = acc[nt][r] + bv;
        v = 0.5f * v * (1.f + erff(v * 0.70710678118f));
        aw[(quad * 4 + r) * 136 + col] = __float2bfloat16(v);
      }
    }
  }
  readA(aw, a, quad, l16);
  zero8(acc); mfma_stage(a, w, acc);
  epi_addx(acc, params + 4864 + l * 128, xr, l16);                 // x += c2
  if (l == 3) {
    int f = *flagp;
    const float* ls = params + 1664;
    float s8[8];
    #pragma unroll
    for (int nt = 0; nt < 8; ++nt) s8[nt] = ls[nt * 16 + l16];
    #pragma unroll
    for (int r = 0; r < 4; ++r) {
      float ss = 0.f;
      #pragma unroll
      for (int nt = 0; nt < 8; ++nt) ss += xr[nt][r] * xr[nt][r];
      ss += __shfl_xor(ss, 1); ss += __shfl_xor(ss, 2);
      ss += __shfl_xor(ss, 4); ss += __shfl_xor(ss, 8);
      float rs = rsqrtf(ss * (1.f / 128.f) + 1e-8f);
      #pragma unroll
      for (int nt = 0; nt < 8; ++nt) {
        size_t off = (size_t)(row0 + quad * 4 + r) * 128 + nt * 16 + l16;
        float o = xr[nt][r] * rs * s8[nt];
        if (f) ((float*)dout)[off] = o; else ((unsigned short*)dout)[off] = bfb(o);
      }
    }
    return;
  }
  #pragma unroll
  for (int nt = 0; nt < 8; ++nt)
    #pragma unroll
    for (int r = 0; r < 4; ++r)
      xg[(size_t)(row0 + quad * 4 + r) * 128 + nt * 16 + l16] = xr[nt][r];
  qkvu_stages(xr, aw, wT, params, l + 1, Ug, Qg, Kg, VTg, row0, quad, l16);
}

// ---------------- HSTU flash: 4-way k-split, 32-row q-tiles, pipelined ----------------
__device__ inline void fk_loadK(const bf16* kbase, bf16x8 (&kf)[2][4], int quad, int l16) {
  #pragma unroll
  for (int kk = 0; kk < 2; ++kk)
    #pragma unroll
    for (int nt = 0; nt < 4; ++nt)
      kf[kk][nt] = *(const bf16x8*)(kbase + (size_t)(nt * 16 + l16) * 128 + kk * 32 + quad * 8);
}

__device__ inline void flash_body(int kt, int ntile, const bf16* kga, const bf16* vba,
    const bf16x8 (&qf)[2][2], const bf16x8 (&kc)[2][4], bf16x8 (&kn)[2][4],
    f32x4 (&oacc)[2][4], f32x4 (&dacc)[2], const bf16x8& onesf,
    bf16* sm, int r0, int quad, int l16) {
  int s0 = kt * 64;
  // V frags issued early (consumed after silu)
  bf16x8 vf[2][4];
  #pragma unroll
  for (int kk = 0; kk < 2; ++kk)
    #pragma unroll
    for (int nt = 0; nt < 4; ++nt)
      vf[kk][nt] = *(const bf16x8*)(vba + (size_t)(nt * 16 + l16) * 2048 + s0 + kk * 32 + quad * 8);
  // S = Q K^T (Q pre-scaled by 1/8)
  f32x4 sacc[2][4] = {};
  #pragma unroll
  for (int kk = 0; kk < 2; ++kk)
    #pragma unroll
    for (int nt = 0; nt < 4; ++nt) {
      sacc[0][nt] = __builtin_amdgcn_mfma_f32_16x16x32_bf16(qf[0][kk], kc[kk][nt], sacc[0][nt], 0, 0, 0);
      sacc[1][nt] = __builtin_amdgcn_mfma_f32_16x16x32_bf16(qf[1][kk], kc[kk][nt], sacc[1][nt], 0, 0, 0);
    }
  // prefetch K for kt+4 (ping-pong buffer, this wave's next tile)
  if (kt + 4 < ntile) fk_loadK(kga + (size_t)(s0 + 256) * 128, kn, quad, l16);
  // silu + (diagonal-tile-only) causal clamp -> sm (wave-private; in-wave lgkm ordering)
  if (kt == ntile - 1) {
    #pragma unroll
    for (int mi = 0; mi < 2; ++mi) {
      int trow = r0 + mi * 16 + quad * 4;
      #pragma unroll
      for (int nt = 0; nt < 4; ++nt) {
        int sc = s0 + nt * 16 + l16;
        #pragma unroll
        for (int r = 0; r < 4; ++r) {
          float v = sacc[mi][nt][r];
          float aa = (sc <= trow + r && v > 0.f) ? v / (1.f + __expf(-v)) : 0.f;
          sm[(mi * 16 + quad * 4 + r) * 72 + nt * 16 + l16] = __float2bfloat16(aa);
        }
      }
    }
  } else {
    #pragma unroll
    for (int mi = 0; mi < 2; ++mi)
      #pragma unroll
      for (int nt = 0; nt < 4; ++nt)
        #pragma unroll
        for (int r = 0; r < 4; ++r) {
          float v = sacc[mi][nt][r];
          float aa = (v > 0.f) ? v / (1.f + __expf(-v)) : 0.f;
          sm[(mi * 16 + quad * 4 + r) * 72 + nt * 16 + l16] = __float2bfloat16(aa);
        }
  }
  // O += S@V; rowsum via ones-column MFMA
  #pragma unroll
  for (int kk = 0; kk < 2; ++kk) {
    bf16x8 af0 = *(const bf16x8*)&sm[l16 * 72 + kk * 32 + quad * 8];
    bf16x8 af1 = *(const bf16x8*)&sm[(16 + l16) * 72 + kk * 32 + quad * 8];
    #pragma unroll
    for (int nt = 0; nt < 4; ++nt) {
      oacc[0][nt] = __builtin_amdgcn_mfma_f32_16x16x32_bf16(af0, vf[kk][nt], oacc[0][nt], 0, 0, 0);
      oacc[1][nt] = __builtin_amdgcn_mfma_f32_16x16x32_bf16(af1, vf[kk][nt], oacc[1][nt], 0, 0, 0);
    }
    dacc[0] = __builtin_amdgcn_mfma_f32_16x16x32_bf16(af0, onesf, dacc[0], 0, 0, 0);
    dacc[1] = __builtin_amdgcn_mfma_f32_16x16x32_bf16(af1, onesf, dacc[1], 0, 0, 0);
  }
}

// grid (64, 16), block 256 = 4 k-split waves over one 32-row q-tile.
// __launch_bounds__ empirical model (5 data points, rounds 0/3/4/5/6):
//   effective waves/EU = arg2 * waves_per_block (clamp 8); VGPR cap = 512/waves_eff.
//   (256,4)->cap 64: spill. (256) uncapped: 168 VGPR -> 2 waves/SIMD, occupancy collapse.
//   (256,1)->waves_eff 4 -> cap 128: round 0 proved this body fits ~120 VGPR at that cap.
// LDS: red[4][2112] f32 partials (stride 65 kills 4-way write conflicts);
//      the per-wave bf16 staging sm overlays the same allocation during the k-loop.
__global__ __launch_bounds__(256, 1) void flash_k(const bf16* __restrict__ Qg,
    const bf16* __restrict__ Kg, const bf16* __restrict__ VTg, float* __restrict__ avg) {
  __shared__ __align__(16) float red[4][2112];    // 33792 B
  int q32 = 63 - (int)blockIdx.x;                 // longest-work blocks dispatch first
  int bh = blockIdx.y, b = bh >> 1, h = bh & 1;
  int tid = threadIdx.x, wv = tid >> 6, lane = tid & 63, quad = lane >> 4, l16 = lane & 15;
  int r0 = q32 * 32;
  bf16* sm = reinterpret_cast<bf16*>(&red[0][0]) + wv * 2304;   // 32x72 per wave
  const bf16* kga = Kg + (size_t)b * 2048 * 128 + h * 64;
  const bf16* vba = VTg + (size_t)bh * 64 * 2048;
  const bf16* qbase = Qg + ((size_t)b * 2048 + r0) * 128 + h * 64;
  bf16x8 qf[2][2];
  #pragma unroll
  for (int mi = 0; mi < 2; ++mi)
    #pragma unroll
    for (int kk = 0; kk < 2; ++kk)
      qf[mi][kk] = *(const bf16x8*)(qbase + (size_t)(mi * 16 + l16) * 128 + kk * 32 + quad * 8);
  bf16x8 onesf;
  #pragma unroll
  for (int j = 0; j < 8; ++j) onesf[j] = (l16 == 0) ? (__bf16)1.0f : (__bf16)0.0f;
  f32x4 oacc[2][4] = {};
  f32x4 dacc[2] = {};
  int ntile = q32 / 2 + 1;
  bf16x8 kA[2][4], kB[2][4];
  int kt = wv;
  if (kt < ntile) {
    fk_loadK(kga + (size_t)kt * 64 * 128, kA, quad, l16);
    while (true) {
      flash_body(kt, ntile, kga, vba, qf, kA, kB, oacc, dacc, onesf, sm, r0, quad, l16);
      kt += 4;
      if (kt >= ntile) break;
      flash_body(kt, ntile, kga, vba, qf, kB, kA, oacc, dacc, onesf, sm, r0, quad, l16);
      kt += 4;
      if (kt >= ntile) break;
    }
  }
  __syncthreads();
  // each wave dumps its partial O (32x64) + row denoms into its red slice
  #pragma unroll
  for (int mi = 0; mi < 2; ++mi) {
    #pragma unroll
    for (int nt = 0; nt < 4; ++nt)
      #pragma unroll
      for (int r = 0; r < 4; ++r)
        red[wv][(mi * 16 + quad * 4 + r) * 65 + nt * 16 + l16] = oacc[mi][nt][r];
    if (l16 == 0) {
      #pragma unroll
      for (int r = 0; r < 4; ++r) red[wv][2080 + mi * 16 + quad * 4 + r] = dacc[mi][r];
    }
  }
  __syncthreads();
  // parallel reduce+normalize: wave wv handles rows [wv*8, wv*8+8)
  #pragma unroll
  for (int j = 0; j < 8; ++j) {
    int row = wv * 8 + j;
    float s = red[0][row * 65 + lane] + red[1][row * 65 + lane]
            + red[2][row * 65 + lane] + red[3][row * 65 + lane];
    float d = red[0][2080 + row] + red[1][2080 + row]
            + red[2][2080 + row] + red[3][2080 + row];
    float inv = (d > 1e-12f) ? 1.f / (d + 1e-8f) : 0.f;
    avg[((size_t)b * 2048 + r0 + row) * 128 + h * 64 + lane] = s * inv;
  }
}

// ---------------- launch ----------------
extern "C" void kernel_launch(void* const* d_in, const int* in_sizes, int n_in,
                              void* d_out, int out_size, void* d_ws, size_t ws_size,
                              hipStream_t stream) {
  const int* seqs = (const int*)d_in[0];
  const void* item = d_in[2];
  const void* pos  = d_in[3];

  float* params = (float*)d_ws;
  int* flagp = (int*)((char*)d_ws + 24 * 1024);
  char* base = (char*)d_ws + 32 * 1024;
  const size_t MB = 1024 * 1024;
  float* x   = (float*)base;                 // 8 MB fp32 residual
  float* av  = (float*)(base + 8 * MB);      // 8 MB fp32 attention out
  bf16* Ug   = (bf16*)(base + 16 * MB);      // 4 MB
  bf16* Qg   = (bf16*)(base + 20 * MB);      // 4 MB (pre-scaled by 1/8)
  bf16* Kg   = (bf16*)(base + 24 * MB);      // 4 MB
  bf16* VTg  = (bf16*)(base + 28 * MB);      // 4 MB  [bh][hd][t]
  bf16* wT   = (bf16*)(base + 32 * MB);      // 28 * 16384 bf16 = 896 KB

  PPtrs pp;
  pp.p[0] = d_in[4];  pp.p[1] = d_in[5];  pp.p[2] = d_in[16]; pp.p[3] = d_in[17];
  pp.p[4] = d_in[22]; pp.p[5] = d_in[7];  pp.p[6] = d_in[9];  pp.p[7] = d_in[11];
  pp.p[8] = d_in[13]; pp.p[9] = d_in[15]; pp.p[10] = d_in[19]; pp.p[11] = d_in[21];
  detect_convert_k<<<1, 256, 0, stream>>>(item, pp, params, flagp);

  WPtrs wp;
  wp.p[0] = d_in[6]; wp.p[1] = d_in[8]; wp.p[2] = d_in[10]; wp.p[3] = d_in[12];
  wp.p[4] = d_in[14]; wp.p[5] = d_in[18]; wp.p[6] = d_in[20];
  transpose_w_k<<<dim3(4, 7), 256, 0, stream>>>(wp, wT, flagp);

  pre_k<<<M / 64, 256, 0, stream>>>(seqs, item, pos, wT, params, x, Ug, Qg, Kg, VTg, flagp);

  for (int l = 0; l < 4; ++l) {
    flash_k<<<dim3(64, 16), 256, 0, stream>>>(Qg, Kg, VTg, av);
    post_k<<<M / 64, 256, 0, stream>>>(l, x, av, Ug, Qg, Kg, VTg, wT, params, d_out, flagp);
  }
}

// Round 8
// 628.868 us; speedup vs baseline: 1.0970x; 1.0970x over previous
//
#include <hip/hip_runtime.h>
#include <hip/hip_bf16.h>

typedef __bf16 bf16x8 __attribute__((ext_vector_type(8)));
typedef float f32x4 __attribute__((ext_vector_type(4)));
using bf16 = __hip_bfloat16;

constexpr int T = 2048;
constexpr int M = 8 * 2048;   // B*T rows

__device__ inline float ldf(const void* p, size_t i, int isf32) {
  if (isf32) return ((const float*)p)[i];
  unsigned u = ((const unsigned short*)p)[i];
  return __uint_as_float(u << 16);
}
__device__ inline float bf2f(unsigned short u) { return __uint_as_float((unsigned)u << 16); }
__device__ inline unsigned short bfb(float x) {
  __hip_bfloat16 h = __float2bfloat16(x);
  return *reinterpret_cast<unsigned short*>(&h);
}

// ---------------- dtype probe + param conversion ----------------
struct PPtrs { const void* p[12]; };

__global__ void detect_convert_k(const void* __restrict__ item, PPtrs ps,
                                 float* __restrict__ params, int* __restrict__ flagp) {
  __shared__ int cnt[4];
  __shared__ int flagLDS;
  int tid = threadIdx.x;
  unsigned short lo = ((const unsigned short*)item)[tid * 2];
  float a = fabsf(bf2f(lo));
  bool okb = (a > 1e-5f) && (a < 0.5f);
  unsigned long long m = __ballot(okb);
  if ((tid & 63) == 0) cnt[tid >> 6] = __popcll(m);
  __syncthreads();
  if (tid == 0) {
    int tot = cnt[0] + cnt[1] + cnt[2] + cnt[3];
    int f = (tot < 128) ? 1 : 0;  // 1 = inputs are float32
    flagLDS = f; *flagp = f;
  }
  __syncthreads();
  int f = flagLDS;
  const int lens[12] = {128, 512, 512, 512, 128, 512, 512, 512, 512, 512, 512, 512};
  int off = 0;
  for (int j = 0; j < 12; ++j) {
    for (int i = tid; i < lens[j]; i += 256) params[off + i] = ldf(ps.p[j], i, f);
    off += lens[j];
  }
}

// ---------------- weight transpose: W[K][N] -> WT[N][K] ----------------
struct WPtrs { const void* p[7]; };

__global__ void transpose_w_k(WPtrs w, bf16* __restrict__ dst, const int* __restrict__ flagp) {
  int f = *flagp;
  int l = blockIdx.x, wi = blockIdx.y;
  const void* s = w.p[wi];
  size_t sbase = (size_t)l * 16384;
  bf16* d = dst + ((size_t)wi * 4 + l) * 16384;
  for (int i = 0; i < 64; ++i) {
    int e = i * 256 + threadIdx.x;                       // e = n*128 + k
    d[e] = __float2bfloat16(ldf(s, sbase + (size_t)(e & 127) * 128 + (e >> 7), f));
  }
}

// ---------------- shared GEMM-stage helpers (all wave-private, no barriers) ----------------
// W fragments straight from global (L2-hot): w[kk][nt] = WT[nt*16+l16][kk*32+quad*8 ..+7]
__device__ inline void issueW(const bf16* wt, bf16x8 (&w)[4][8], int quad, int l16) {
  #pragma unroll
  for (int kk = 0; kk < 4; ++kk)
    #pragma unroll
    for (int nt = 0; nt < 8; ++nt)
      w[kk][nt] = *(const bf16x8*)(wt + (size_t)(nt * 16 + l16) * 128 + kk * 32 + quad * 8);
}
__device__ inline void mfma_stage(const bf16x8 (&a)[4], const bf16x8 (&w)[4][8], f32x4 (&acc)[8]) {
  #pragma unroll
  for (int kk = 0; kk < 4; ++kk)
    #pragma unroll
    for (int nt = 0; nt < 8; ++nt)
      acc[nt] = __builtin_amdgcn_mfma_f32_16x16x32_bf16(a[kk], w[kk][nt], acc[nt], 0, 0, 0);
}
__device__ inline void zero8(f32x4 (&acc)[8]) {
  #pragma unroll
  for (int i = 0; i < 8; ++i) acc[i] = (f32x4){0.f, 0.f, 0.f, 0.f};
}
__device__ inline void readA(const bf16* aw, bf16x8 (&a)[4], int quad, int l16) {
  #pragma unroll
  for (int kk = 0; kk < 4; ++kk)
    a[kk] = *(const bf16x8*)&aw[l16 * 136 + kk * 32 + quad * 8];
}
// xr[nt][r] C-layout: row quad*4+r, col nt*16+l16. Builds A = rms(row)*scale into aw.
__device__ inline void buildA_rms(const float (&xr)[8][4], const float* scale, bf16* aw,
                                  int quad, int l16) {
  float s8[8];
  #pragma unroll
  for (int nt = 0; nt < 8; ++nt) s8[nt] = scale[nt * 16 + l16];
  #pragma unroll
  for (int r = 0; r < 4; ++r) {
    float ss = 0.f;
    #pragma unroll
    for (int nt = 0; nt < 8; ++nt) ss += xr[nt][r] * xr[nt][r];
    ss += __shfl_xor(ss, 1); ss += __shfl_xor(ss, 2);
    ss += __shfl_xor(ss, 4); ss += __shfl_xor(ss, 8);
    float rs = rsqrtf(ss * (1.f / 128.f) + 1e-8f);
    #pragma unroll
    for (int nt = 0; nt < 8; ++nt)
      aw[(quad * 4 + r) * 136 + nt * 16 + l16] = __float2bfloat16(xr[nt][r] * rs * s8[nt]);
  }
}
__device__ inline void epi_silu_store(const f32x4 (&acc)[8], const float* bias, bf16* outg,
                                      int row0, int quad, int l16, float mulf) {
  #pragma unroll
  for (int nt = 0; nt < 8; ++nt) {
    int col = nt * 16 + l16; float bv = bias[col];
    #pragma unroll
    for (int r = 0; r < 4; ++r) {
      float v = acc[nt][r] + bv;
      v = v / (1.f + __expf(-v)) * mulf;
      outg[(size_t)(row0 + quad * 4 + r) * 128 + col] = __float2bfloat16(v);
    }
  }
}
__device__ inline void epi_silu_vt(const f32x4 (&acc)[8], const float* bias, bf16* vtg,
                                   int row0, int quad, int l16) {
  #pragma unroll
  for (int nt = 0; nt < 8; ++nt) {
    int col = nt * 16 + l16; float bv = bias[col];
    int h = col >> 6, hd = col & 63;
    #pragma unroll
    for (int r = 0; r < 4; ++r) {
      int gr = row0 + quad * 4 + r; int b = gr >> 11, t = gr & 2047;
      float v = acc[nt][r] + bv; v = v / (1.f + __expf(-v));
      vtg[((size_t)(b * 2 + h) * 64 + hd) * 2048 + t] = __float2bfloat16(v);
    }
  }
}
__device__ inline void epi_addx(const f32x4 (&acc)[8], const float* bias, float (&xr)[8][4],
                                int l16) {
  #pragma unroll
  for (int nt = 0; nt < 8; ++nt) {
    float bv = bias[nt * 16 + l16];
    #pragma unroll
    for (int r = 0; r < 4; ++r) xr[nt][r] += acc[nt][r] + bv;
  }
}

// QKVU stages for layer lnext: A = rms(xr)*ln1 shared across the 4 weight matrices.
// Q is pre-scaled by 0.125 (exact in bf16) so flash skips the per-element logits scale.
__device__ inline void qkvu_stages(const float (&xr)[8][4], bf16* aw, const bf16* wT,
    const float* params, int lnext, bf16* Ug, bf16* Qg, bf16* Kg, bf16* VTg,
    int row0, int quad, int l16) {
  buildA_rms(xr, params + 128 + lnext * 128, aw, quad, l16);
  bf16x8 a[4]; readA(aw, a, quad, l16);
  bf16x8 w[4][8]; f32x4 acc[8];
  const float* pb = params + 1792;
  issueW(wT + (size_t)(0 * 4 + lnext) * 16384, w, quad, l16);      // U
  zero8(acc); mfma_stage(a, w, acc);
  issueW(wT + (size_t)(1 * 4 + lnext) * 16384, w, quad, l16);      // V
  epi_silu_store(acc, pb + 0 * 512 + lnext * 128, Ug, row0, quad, l16, 1.f);
  zero8(acc); mfma_stage(a, w, acc);
  issueW(wT + (size_t)(2 * 4 + lnext) * 16384, w, quad, l16);      // Q
  epi_silu_vt(acc, pb + 1 * 512 + lnext * 128, VTg, row0, quad, l16);
  zero8(acc); mfma_stage(a, w, acc);
  issueW(wT + (size_t)(3 * 4 + lnext) * 16384, w, quad, l16);      // K
  epi_silu_store(acc, pb + 2 * 512 + lnext * 128, Qg, row0, quad, l16, 0.125f);
  zero8(acc); mfma_stage(a, w, acc);
  epi_silu_store(acc, pb + 3 * 512 + lnext * 128, Kg, row0, quad, l16, 1.f);
}

// ---------------- pre: embed + rms + QKVU(0). Barrier-free, wave owns 16 rows ----------------
__global__ __launch_bounds__(256) void pre_k(const int* __restrict__ seqs,
    const void* __restrict__ item, const void* __restrict__ pos, const bf16* __restrict__ wT,
    const float* __restrict__ params, float* __restrict__ xg, bf16* __restrict__ Ug,
    bf16* __restrict__ Qg, bf16* __restrict__ Kg, bf16* __restrict__ VTg,
    const int* __restrict__ flagp) {
  __shared__ __align__(16) bf16 awAll[4][16 * 136 + 8];
  int f = *flagp;
  int tid = threadIdx.x, wv = tid >> 6, lane = tid & 63, quad = lane >> 4, l16 = lane & 15;
  bf16* aw = awAll[wv];
  int row0 = blockIdx.x * 64 + wv * 16;
  int idxs[4];
  #pragma unroll
  for (int r = 0; r < 4; ++r) idxs[r] = seqs[row0 + quad * 4 + r];
  float xr[8][4];
  #pragma unroll
  for (int nt = 0; nt < 8; ++nt) {
    int col = nt * 16 + l16;
    #pragma unroll
    for (int r = 0; r < 4; ++r) {
      int gr = row0 + quad * 4 + r; int t = gr & 2047;
      xr[nt][r] = ldf(item, (size_t)idxs[r] * 128 + col, f)
                + ldf(pos, (size_t)(t + 1) * 128 + col, f);
    }
  }
  {  // x = rms(e)*emb_s
    float s8[8];
    #pragma unroll
    for (int nt = 0; nt < 8; ++nt) s8[nt] = params[nt * 16 + l16];
    #pragma unroll
    for (int r = 0; r < 4; ++r) {
      float ss = 0.f;
      #pragma unroll
      for (int nt = 0; nt < 8; ++nt) ss += xr[nt][r] * xr[nt][r];
      ss += __shfl_xor(ss, 1); ss += __shfl_xor(ss, 2);
      ss += __shfl_xor(ss, 4); ss += __shfl_xor(ss, 8);
      float rs = rsqrtf(ss * (1.f / 128.f) + 1e-8f);
      #pragma unroll
      for (int nt = 0; nt < 8; ++nt) xr[nt][r] *= rs * s8[nt];
    }
  }
  #pragma unroll
  for (int nt = 0; nt < 8; ++nt)
    #pragma unroll
    for (int r = 0; r < 4; ++r)
      xg[(size_t)(row0 + quad * 4 + r) * 128 + nt * 16 + l16] = xr[nt][r];
  qkvu_stages(xr, aw, wT, params, 0, Ug, Qg, Kg, VTg, row0, quad, l16);
}

// ---------------- post: f2+FFN for layer l, then QKVU(l+1) or final out ----------------
__global__ __launch_bounds__(256) void post_k(int l, float* __restrict__ xg,
    const float* __restrict__ avg, bf16* __restrict__ Ug, bf16* __restrict__ Qg,
    bf16* __restrict__ Kg, bf16* __restrict__ VTg, const bf16* __restrict__ wT,
    const float* __restrict__ params, void* __restrict__ dout, const int* __restrict__ flagp) {
  __shared__ __align__(16) bf16 awAll[4][16 * 136 + 8];
  int tid = threadIdx.x, wv = tid >> 6, lane = tid & 63, quad = lane >> 4, l16 = lane & 15;
  bf16* aw = awAll[wv];
  int row0 = blockIdx.x * 64 + wv * 16;
  bf16x8 w[4][8]; f32x4 acc[8];
  issueW(wT + (size_t)(16 + l) * 16384, w, quad, l16);             // f2
  float xr[8][4], av[8][4], uu[8][4];
  #pragma unroll
  for (int nt = 0; nt < 8; ++nt) {
    int col = nt * 16 + l16;
    #pragma unroll
    for (int r = 0; r < 4; ++r) {
      size_t off = (size_t)(row0 + quad * 4 + r) * 128 + col;
      xr[nt][r] = xg[off];
      av[nt][r] = avg[off];
      uu[nt][r] = bf2f(((const unsigned short*)Ug)[off]);
    }
  }
  {  // A = rms(av)*hstu_s*U
    const float* hs = params + 640 + l * 128;
    float s8[8];
    #pragma unroll
    for (int nt = 0; nt < 8; ++nt) s8[nt] = hs[nt * 16 + l16];
    #pragma unroll
    for (int r = 0; r < 4; ++r) {
      float ss = 0.f;
      #pragma unroll
      for (int nt = 0; nt < 8; ++nt) ss += av[nt][r] * av[nt][r];
      ss += __shfl_xor(ss, 1); ss += __shfl_xor(ss, 2);
      ss += __shfl_xor(ss, 4); ss += __shfl_xor(ss, 8);
      float rs = rsqrtf(ss * (1.f / 128.f) + 1e-8f);
      #pragma unroll
      for (int nt = 0; nt < 8; ++nt)
        aw[(quad * 4 + r) * 136 + nt * 16 + l16] =
            __float2bfloat16(av[nt][r] * rs * s8[nt] * uu[nt][r]);
    }
  }
  bf16x8 a[4]; readA(aw, a, quad, l16);
  zero8(acc); mfma_stage(a, w, acc);
  issueW(wT + (size_t)(20 + l) * 16384, w, quad, l16);             // c1
  epi_addx(acc, params + 3840 + l * 128, xr, l16);                 // x += f2
  buildA_rms(xr, params + 1152 + l * 128, aw, quad, l16);          // ln2
  readA(aw, a, quad, l16);
  zero8(acc); mfma_stage(a, w, acc);
  issueW(wT + (size_t)(24 + l) * 16384, w, quad, l16);             // c2
  {  // gelu -> aw (A of c2)
    const float* bb = params + 4352 + l * 128;
    #pragma unroll
    for (int nt = 0; nt < 8; ++nt) {
      int col = nt * 16 + l16; float bv = bb[col];
      #pragma unroll
      for (int r = 0; r < 4; ++r) {
        float v = acc[nt][r] + bv;
        v = 0.5f * v * (1.f + erff(v * 0.70710678118f));
        aw[(quad * 4 + r) * 136 + col] = __float2bfloat16(v);
      }
    }
  }
  readA(aw, a, quad, l16);
  zero8(acc); mfma_stage(a, w, acc);
  epi_addx(acc, params + 4864 + l * 128, xr, l16);                 // x += c2
  if (l == 3) {
    int f = *flagp;
    const float* ls = params + 1664;
    float s8[8];
    #pragma unroll
    for (int nt = 0; nt < 8; ++nt) s8[nt] = ls[nt * 16 + l16];
    #pragma unroll
    for (int r = 0; r < 4; ++r) {
      float ss = 0.f;
      #pragma unroll
      for (int nt = 0; nt < 8; ++nt) ss += xr[nt][r] * xr[nt][r];
      ss += __shfl_xor(ss, 1); ss += __shfl_xor(ss, 2);
      ss += __shfl_xor(ss, 4); ss += __shfl_xor(ss, 8);
      float rs = rsqrtf(ss * (1.f / 128.f) + 1e-8f);
      #pragma unroll
      for (int nt = 0; nt < 8; ++nt) {
        size_t off = (size_t)(row0 + quad * 4 + r) * 128 + nt * 16 + l16;
        float o = xr[nt][r] * rs * s8[nt];
        if (f) ((float*)dout)[off] = o; else ((unsigned short*)dout)[off] = bfb(o);
      }
    }
    return;
  }
  #pragma unroll
  for (int nt = 0; nt < 8; ++nt)
    #pragma unroll
    for (int r = 0; r < 4; ++r)
      xg[(size_t)(row0 + quad * 4 + r) * 128 + nt * 16 + l16] = xr[nt][r];
  qkvu_stages(xr, aw, wT, params, l + 1, Ug, Qg, Kg, VTg, row0, quad, l16);
}

// ---------------- HSTU flash: 4-way k-split, 32-row q-tiles, pipelined ----------------
__device__ inline void fk_loadK(const bf16* kbase, bf16x8 (&kf)[2][4], int quad, int l16) {
  #pragma unroll
  for (int kk = 0; kk < 2; ++kk)
    #pragma unroll
    for (int nt = 0; nt < 4; ++nt)
      kf[kk][nt] = *(const bf16x8*)(kbase + (size_t)(nt * 16 + l16) * 128 + kk * 32 + quad * 8);
}

__device__ inline void flash_body(int kt, int ntile, const bf16* kga, const bf16* vba,
    const bf16x8 (&qf)[2][2], const bf16x8 (&kc)[2][4], bf16x8 (&kn)[2][4],
    f32x4 (&oacc)[2][4], f32x4 (&dacc)[2], const bf16x8& onesf,
    bf16* sm, int r0, int quad, int l16) {
  int s0 = kt * 64;
  // V frags issued early (consumed after silu)
  bf16x8 vf[2][4];
  #pragma unroll
  for (int kk = 0; kk < 2; ++kk)
    #pragma unroll
    for (int nt = 0; nt < 4; ++nt)
      vf[kk][nt] = *(const bf16x8*)(vba + (size_t)(nt * 16 + l16) * 2048 + s0 + kk * 32 + quad * 8);
  // S = Q K^T (Q pre-scaled by 1/8)
  f32x4 sacc[2][4] = {};
  #pragma unroll
  for (int kk = 0; kk < 2; ++kk)
    #pragma unroll
    for (int nt = 0; nt < 4; ++nt) {
      sacc[0][nt] = __builtin_amdgcn_mfma_f32_16x16x32_bf16(qf[0][kk], kc[kk][nt], sacc[0][nt], 0, 0, 0);
      sacc[1][nt] = __builtin_amdgcn_mfma_f32_16x16x32_bf16(qf[1][kk], kc[kk][nt], sacc[1][nt], 0, 0, 0);
    }
  // prefetch K for kt+4 (ping-pong buffer, this wave's next tile)
  if (kt + 4 < ntile) fk_loadK(kga + (size_t)(s0 + 256) * 128, kn, quad, l16);
  // silu + (diagonal-tile-only) causal clamp -> sm (wave-private; in-wave lgkm ordering)
  if (kt == ntile - 1) {
    #pragma unroll
    for (int mi = 0; mi < 2; ++mi) {
      int trow = r0 + mi * 16 + quad * 4;
      #pragma unroll
      for (int nt = 0; nt < 4; ++nt) {
        int sc = s0 + nt * 16 + l16;
        #pragma unroll
        for (int r = 0; r < 4; ++r) {
          float v = sacc[mi][nt][r];
          float aa = (sc <= trow + r && v > 0.f) ? v / (1.f + __expf(-v)) : 0.f;
          sm[(mi * 16 + quad * 4 + r) * 72 + nt * 16 + l16] = __float2bfloat16(aa);
        }
      }
    }
  } else {
    #pragma unroll
    for (int mi = 0; mi < 2; ++mi)
      #pragma unroll
      for (int nt = 0; nt < 4; ++nt)
        #pragma unroll
        for (int r = 0; r < 4; ++r) {
          float v = sacc[mi][nt][r];
          float aa = (v > 0.f) ? v / (1.f + __expf(-v)) : 0.f;
          sm[(mi * 16 + quad * 4 + r) * 72 + nt * 16 + l16] = __float2bfloat16(aa);
        }
  }
  // O += S@V; rowsum via ones-column MFMA
  #pragma unroll
  for (int kk = 0; kk < 2; ++kk) {
    bf16x8 af0 = *(const bf16x8*)&sm[l16 * 72 + kk * 32 + quad * 8];
    bf16x8 af1 = *(const bf16x8*)&sm[(16 + l16) * 72 + kk * 32 + quad * 8];
    #pragma unroll
    for (int nt = 0; nt < 4; ++nt) {
      oacc[0][nt] = __builtin_amdgcn_mfma_f32_16x16x32_bf16(af0, vf[kk][nt], oacc[0][nt], 0, 0, 0);
      oacc[1][nt] = __builtin_amdgcn_mfma_f32_16x16x32_bf16(af1, vf[kk][nt], oacc[1][nt], 0, 0, 0);
    }
    dacc[0] = __builtin_amdgcn_mfma_f32_16x16x32_bf16(af0, onesf, dacc[0], 0, 0, 0);
    dacc[1] = __builtin_amdgcn_mfma_f32_16x16x32_bf16(af1, onesf, dacc[1], 0, 0, 0);
  }
}

// grid (64, 16), block 256 = 4 k-split waves over one 32-row q-tile.
// __launch_bounds__ empirical model (6 data points, rounds 0/3/4/5/6/7):
//   effective waves/EU target = 2 * arg2; VGPR cap = 512/(2*arg2).
//   (256,4)->cap 64: spill. (256,1)/(256)->cap 256/none: 168 VGPR -> 2 waves/SIMD.
//   (256,2)->cap 128: round 0's identical per-wave body compiled to 120 under this cap.
//   At <=128 VGPR: 4 waves/SIMD -> 4 blocks/CU -> all 1024 blocks co-resident.
// LDS: red[4][2112] f32 partials (stride 65 kills 4-way write conflicts);
//      the per-wave bf16 staging sm overlays the same allocation during the k-loop.
__global__ __launch_bounds__(256, 2) void flash_k(const bf16* __restrict__ Qg,
    const bf16* __restrict__ Kg, const bf16* __restrict__ VTg, float* __restrict__ avg) {
  __shared__ __align__(16) float red[4][2112];    // 33792 B
  int q32 = 63 - (int)blockIdx.x;                 // longest-work blocks dispatch first
  int bh = blockIdx.y, b = bh >> 1, h = bh & 1;
  int tid = threadIdx.x, wv = tid >> 6, lane = tid & 63, quad = lane >> 4, l16 = lane & 15;
  int r0 = q32 * 32;
  bf16* sm = reinterpret_cast<bf16*>(&red[0][0]) + wv * 2304;   // 32x72 per wave
  const bf16* kga = Kg + (size_t)b * 2048 * 128 + h * 64;
  const bf16* vba = VTg + (size_t)bh * 64 * 2048;
  const bf16* qbase = Qg + ((size_t)b * 2048 + r0) * 128 + h * 64;
  bf16x8 qf[2][2];
  #pragma unroll
  for (int mi = 0; mi < 2; ++mi)
    #pragma unroll
    for (int kk = 0; kk < 2; ++kk)
      qf[mi][kk] = *(const bf16x8*)(qbase + (size_t)(mi * 16 + l16) * 128 + kk * 32 + quad * 8);
  bf16x8 onesf;
  #pragma unroll
  for (int j = 0; j < 8; ++j) onesf[j] = (l16 == 0) ? (__bf16)1.0f : (__bf16)0.0f;
  f32x4 oacc[2][4] = {};
  f32x4 dacc[2] = {};
  int ntile = q32 / 2 + 1;
  bf16x8 kA[2][4], kB[2][4];
  int kt = wv;
  if (kt < ntile) {
    fk_loadK(kga + (size_t)kt * 64 * 128, kA, quad, l16);
    while (true) {
      flash_body(kt, ntile, kga, vba, qf, kA, kB, oacc, dacc, onesf, sm, r0, quad, l16);
      kt += 4;
      if (kt >= ntile) break;
      flash_body(kt, ntile, kga, vba, qf, kB, kA, oacc, dacc, onesf, sm, r0, quad, l16);
      kt += 4;
      if (kt >= ntile) break;
    }
  }
  __syncthreads();
  // each wave dumps its partial O (32x64) + row denoms into its red slice
  #pragma unroll
  for (int mi = 0; mi < 2; ++mi) {
    #pragma unroll
    for (int nt = 0; nt < 4; ++nt)
      #pragma unroll
      for (int r = 0; r < 4; ++r)
        red[wv][(mi * 16 + quad * 4 + r) * 65 + nt * 16 + l16] = oacc[mi][nt][r];
    if (l16 == 0) {
      #pragma unroll
      for (int r = 0; r < 4; ++r) red[wv][2080 + mi * 16 + quad * 4 + r] = dacc[mi][r];
    }
  }
  __syncthreads();
  // parallel reduce+normalize: wave wv handles rows [wv*8, wv*8+8)
  #pragma unroll
  for (int j = 0; j < 8; ++j) {
    int row = wv * 8 + j;
    float s = red[0][row * 65 + lane] + red[1][row * 65 + lane]
            + red[2][row * 65 + lane] + red[3][row * 65 + lane];
    float d = red[0][2080 + row] + red[1][2080 + row]
            + red[2][2080 + row] + red[3][2080 + row];
    float inv = (d > 1e-12f) ? 1.f / (d + 1e-8f) : 0.f;
    avg[((size_t)b * 2048 + r0 + row) * 128 + h * 64 + lane] = s * inv;
  }
}

// ---------------- launch ----------------
extern "C" void kernel_launch(void* const* d_in, const int* in_sizes, int n_in,
                              void* d_out, int out_size, void* d_ws, size_t ws_size,
                              hipStream_t stream) {
  const int* seqs = (const int*)d_in[0];
  const void* item = d_in[2];
  const void* pos  = d_in[3];

  float* params = (float*)d_ws;
  int* flagp = (int*)((char*)d_ws + 24 * 1024);
  char* base = (char*)d_ws + 32 * 1024;
  const size_t MB = 1024 * 1024;
  float* x   = (float*)base;                 // 8 MB fp32 residual
  float* av  = (float*)(base + 8 * MB);      // 8 MB fp32 attention out
  bf16* Ug   = (bf16*)(base + 16 * MB);      // 4 MB
  bf16* Qg   = (bf16*)(base + 20 * MB);      // 4 MB (pre-scaled by 1/8)
  bf16* Kg   = (bf16*)(base + 24 * MB);      // 4 MB
  bf16* VTg  = (bf16*)(base + 28 * MB);      // 4 MB  [bh][hd][t]
  bf16* wT   = (bf16*)(base + 32 * MB);      // 28 * 16384 bf16 = 896 KB

  PPtrs pp;
  pp.p[0] = d_in[4];  pp.p[1] = d_in[5];  pp.p[2] = d_in[16]; pp.p[3] = d_in[17];
  pp.p[4] = d_in[22]; pp.p[5] = d_in[7];  pp.p[6] = d_in[9];  pp.p[7] = d_in[11];
  pp.p[8] = d_in[13]; pp.p[9] = d_in[15]; pp.p[10] = d_in[19]; pp.p[11] = d_in[21];
  detect_convert_k<<<1, 256, 0, stream>>>(item, pp, params, flagp);

  WPtrs wp;
  wp.p[0] = d_in[6]; wp.p[1] = d_in[8]; wp.p[2] = d_in[10]; wp.p[3] = d_in[12];
  wp.p[4] = d_in[14]; wp.p[5] = d_in[18]; wp.p[6] = d_in[20];
  transpose_w_k<<<dim3(4, 7), 256, 0, stream>>>(wp, wT, flagp);

  pre_k<<<M / 64, 256, 0, stream>>>(seqs, item, pos, wT, params, x, Ug, Qg, Kg, VTg, flagp);

  for (int l = 0; l < 4; ++l) {
    flash_k<<<dim3(64, 16), 256, 0, stream>>>(Qg, Kg, VTg, av);
    post_k<<<M / 64, 256, 0, stream>>>(l, x, av, Ug, Qg, Kg, VTg, wT, params, d_out, flagp);
  }
}